// Round 1
// baseline (112.278 us; speedup 1.0000x reference)
//
#include <hip/hip_runtime.h>

// PolyLinear: out[i] = b + sum_j W[j] * prod_k x_aug[i, idx[j,k]]
// Deterministic lex-order enumeration: deg1 W[0..31], deg2 W[32..559] (a<=b),
// deg3 W[560..6543] (a<=b<=c). Factorization per row:
//   acc = sum_a W1[a]*x_a
//       + sum_{a<=b} (x_a*x_b) * ( W2[a,b] + sum_{c>=b} W3[a,b,c]*x_c )
//
// V2 vs V1 (82 us): V1 was SMEM-latency-bound (wave-uniform W loads ->
// s_load batches with lgkmcnt(0) full drains, only 2 waves/SIMD to hide
// ~300cy L2 latency -> ~4% VALU util). Changes:
//   1. W staged to LDS once per block; inner loop uses ds_read (merged b128),
//      which pipelines under partial lgkmcnt unlike SMEM.
//   2. 2 rows per lane: each weight feeds 2 independent FMA chains
//      (halves weight reads per FLOP, covers 4cy FMA latency at 2cy issue).
//   3. 16-way term split (balanced at (a,b)-pair granularity), 1024-thread
//      blocks, grid=256 -> 1 block/CU, 16 waves/CU = 4 waves/SIMD.

#define NPART 16
#define TOTAL3 5984

__device__ __forceinline__ constexpr int off2(int a, int b) {
    // deg2 base 32; pairs (a<=b) lex order
    return 32 + 32 * a - (a * (a - 1)) / 2 + (b - a);
}

__device__ __forceinline__ constexpr int off3(int a, int b, int c) {
    // deg3 base 560; triples (a<=b<=c) lex order.
    // g3[a] = #triples with first index < a
    constexpr int g3[32] = {
        0,    528,  1024, 1489, 1924, 2330, 2708, 3059,
        3384, 3684, 3960, 4213, 4444, 4654, 4844, 5015,
        5168, 5304, 5424, 5529, 5620, 5698, 5764, 5819,
        5864, 5900, 5928, 5949, 5964, 5974, 5980, 5983};
    return 560 + g3[a] + 32 * (b - a) - ((b * (b - 1)) / 2 - (a * (a - 1)) / 2) + (c - b);
}

// #deg3 triples strictly before pair (a,b)'s c-run in lex order
__device__ __forceinline__ constexpr int cum3(int a, int b) {
    return off3(a, b, b) - 560;
}

// Balanced static ownership of pair (a,b): parts get ~equal deg3-FMA counts.
__device__ __forceinline__ constexpr int owner_of(int a, int b) {
    return (cum3(a, b) * NPART) / TOTAL3;  // monotone, 0..NPART-1
}

template <int PART>
__device__ __forceinline__ void eval_part(const float* __restrict__ Wl,
                                          const float (&x0)[32],
                                          const float (&x1)[32],
                                          float& acc0, float& acc1) {
    float a0 = 0.0f, a1 = 0.0f;
#pragma unroll
    for (int a = 0; a < 32; ++a) {
#pragma unroll
        for (int b = a; b < 32; ++b) {
            const int own = owner_of(a, b);  // folds post-unroll
            if (own == PART) {
                const float xa0 = x0[a], xa1 = x1[a];
                if (a == b) {  // attach deg1 term for feature a here
                    const float w1 = Wl[a];
                    a0 = __builtin_fmaf(w1, xa0, a0);
                    a1 = __builtin_fmaf(w1, xa1, a1);
                }
                float s0 = Wl[off2(a, b)];  // deg2 weight seeds the chain
                float s1 = s0;
#pragma unroll
                for (int c = b; c < 32; ++c) {
                    const float w = Wl[off3(a, b, c)];  // one LDS read, 2 FMAs
                    s0 = __builtin_fmaf(w, x0[c], s0);
                    s1 = __builtin_fmaf(w, x1[c], s1);
                }
                const float p0 = xa0 * x0[b];
                const float p1 = xa1 * x1[b];
                a0 = __builtin_fmaf(p0, s0, a0);
                a1 = __builtin_fmaf(p1, s1, a1);
            }
        }
    }
    acc0 = a0;
    acc1 = a1;
}

// Block: 1024 threads = 16 waves, one balanced part each, same 128 rows.
// Each lane owns 2 rows (lane, lane+64). LDS reduce across waves.
__global__ __launch_bounds__(1024, 4) void PolyLinear_40218073760341_kernel(
    const float* __restrict__ X,   // (rows, 32)
    const float* __restrict__ W,   // (6544,)
    const float* __restrict__ Bp,  // (1,)
    float* __restrict__ out)       // (rows,)
{
    const int lane = threadIdx.x & 63;
    const int wave = threadIdx.x >> 6;  // part id 0..15
    const long base = (long)blockIdx.x * 128;

    __shared__ float Wl[6544];          // 26.2 KB staged weights
    __shared__ float partial[16][128];  // 8 KB reduce buffer

    // Stage W -> LDS (coalesced float4; 1636 vec4 over 1024 threads)
    {
        const float4* Wg = (const float4*)W;
        float4* Wd = (float4*)Wl;
        for (int i = threadIdx.x; i < 1636; i += 1024) Wd[i] = Wg[i];
    }

    // Load this lane's 2 rows into registers (coalesced float4).
    float x0[32], x1[32];
    {
        const float4* xr0 = (const float4*)(X + (base + lane) * 32);
        const float4* xr1 = (const float4*)(X + (base + 64 + lane) * 32);
#pragma unroll
        for (int i = 0; i < 8; ++i) {
            const float4 v = xr0[i];
            x0[4 * i + 0] = v.x; x0[4 * i + 1] = v.y;
            x0[4 * i + 2] = v.z; x0[4 * i + 3] = v.w;
            const float4 u = xr1[i];
            x1[4 * i + 0] = u.x; x1[4 * i + 1] = u.y;
            x1[4 * i + 2] = u.z; x1[4 * i + 3] = u.w;
        }
    }
    __syncthreads();  // Wl ready

    float acc0 = 0.0f, acc1 = 0.0f;
#define EVAL_CASE(P) case P: eval_part<P>(Wl, x0, x1, acc0, acc1); break;
    switch (wave) {
        EVAL_CASE(0)  EVAL_CASE(1)  EVAL_CASE(2)  EVAL_CASE(3)
        EVAL_CASE(4)  EVAL_CASE(5)  EVAL_CASE(6)  EVAL_CASE(7)
        EVAL_CASE(8)  EVAL_CASE(9)  EVAL_CASE(10) EVAL_CASE(11)
        EVAL_CASE(12) EVAL_CASE(13) EVAL_CASE(14) EVAL_CASE(15)
    }
#undef EVAL_CASE

    partial[wave][lane] = acc0;
    partial[wave][64 + lane] = acc1;
    __syncthreads();

    if (threadIdx.x < 128) {
        float r = Bp[0];
#pragma unroll
        for (int w = 0; w < 16; ++w) r += partial[w][threadIdx.x];
        out[base + threadIdx.x] = r;
    }
}

extern "C" void kernel_launch(void* const* d_in, const int* in_sizes, int n_in,
                              void* d_out, int out_size, void* d_ws, size_t ws_size,
                              hipStream_t stream) {
    const float* X  = (const float*)d_in[0];  // (32768, 32) fp32
    const float* W  = (const float*)d_in[1];  // (1, 6544) fp32
    const float* Bp = (const float*)d_in[2];  // (1,) fp32
    // d_in[3] = idx — deterministic, unused.
    float* out = (float*)d_out;

    const int rows = in_sizes[0] / 32;  // 32768
    const int grid = rows / 128;        // 256 blocks of 1024 threads
    PolyLinear_40218073760341_kernel<<<grid, 1024, 0, stream>>>(X, W, Bp, out);
}

// Round 2
// 104.909 us; speedup vs baseline: 1.0702x; 1.0702x over previous
//
#include <hip/hip_runtime.h>

// PolyLinear: out[i] = b + sum_j W[j] * prod_k x_aug[i, idx[j,k]]
// Deterministic lex-order enumeration: deg1 W[0..31], deg2 W[32..559] (a<=b),
// deg3 W[560..6543] (a<=b<=c). Factorization per row:
//   acc = sum_a W1[a]*x_a
//       + sum_{a<=b} (x_a*x_b) * ( W2[a,b] + sum_{c>=b} W3[a,b,c]*x_c )
//
// V3 vs V2 (51 us warm): V2 spilled — VGPR_Count=64 while x0[]+x1[] alone
// need 64 VGPRs; WRITE_SIZE 67MB = 256 B/thread of scratch writes (the x
// arrays), FETCH 26MB = X + scratch re-reads. __launch_bounds__(1024,4)
// produced a 64-VGPR cap (8 waves/EU budget), not the 128 I expected.
// Fix: __launch_bounds__(1024) only -> allocator bounded by block residency
// (16 waves/CU => 128 VGPR cap), ~95 VGPR demand fits, no spill.
// Structure unchanged: W in LDS, 2 rows/lane, 16-way balanced term split,
// grid=256 blocks of 1024 => 1 block/CU, 4 waves/SIMD.

#define NPART 16
#define TOTAL3 5984

__device__ __forceinline__ constexpr int off2(int a, int b) {
    // deg2 base 32; pairs (a<=b) lex order
    return 32 + 32 * a - (a * (a - 1)) / 2 + (b - a);
}

__device__ __forceinline__ constexpr int off3(int a, int b, int c) {
    // deg3 base 560; triples (a<=b<=c) lex order.
    // g3[a] = #triples with first index < a
    constexpr int g3[32] = {
        0,    528,  1024, 1489, 1924, 2330, 2708, 3059,
        3384, 3684, 3960, 4213, 4444, 4654, 4844, 5015,
        5168, 5304, 5424, 5529, 5620, 5698, 5764, 5819,
        5864, 5900, 5928, 5949, 5964, 5974, 5980, 5983};
    return 560 + g3[a] + 32 * (b - a) - ((b * (b - 1)) / 2 - (a * (a - 1)) / 2) + (c - b);
}

// #deg3 triples strictly before pair (a,b)'s c-run in lex order
__device__ __forceinline__ constexpr int cum3(int a, int b) {
    return off3(a, b, b) - 560;
}

// Balanced static ownership of pair (a,b): parts get ~equal deg3-FMA counts.
__device__ __forceinline__ constexpr int owner_of(int a, int b) {
    return (cum3(a, b) * NPART) / TOTAL3;  // monotone, 0..NPART-1
}

template <int PART>
__device__ __forceinline__ void eval_part(const float* __restrict__ Wl,
                                          const float (&x0)[32],
                                          const float (&x1)[32],
                                          float& acc0, float& acc1) {
    float a0 = 0.0f, a1 = 0.0f;
#pragma unroll
    for (int a = 0; a < 32; ++a) {
#pragma unroll
        for (int b = a; b < 32; ++b) {
            const int own = owner_of(a, b);  // folds post-unroll
            if (own == PART) {
                const float xa0 = x0[a], xa1 = x1[a];
                if (a == b) {  // attach deg1 term for feature a here
                    const float w1 = Wl[a];
                    a0 = __builtin_fmaf(w1, xa0, a0);
                    a1 = __builtin_fmaf(w1, xa1, a1);
                }
                float s0 = Wl[off2(a, b)];  // deg2 weight seeds the chain
                float s1 = s0;
#pragma unroll
                for (int c = b; c < 32; ++c) {
                    const float w = Wl[off3(a, b, c)];  // one LDS read, 2 FMAs
                    s0 = __builtin_fmaf(w, x0[c], s0);
                    s1 = __builtin_fmaf(w, x1[c], s1);
                }
                const float p0 = xa0 * x0[b];
                const float p1 = xa1 * x1[b];
                a0 = __builtin_fmaf(p0, s0, a0);
                a1 = __builtin_fmaf(p1, s1, a1);
            }
        }
    }
    acc0 = a0;
    acc1 = a1;
}

// Block: 1024 threads = 16 waves, one balanced part each, same 128 rows.
// Each lane owns 2 rows (lane, lane+64). LDS reduce across waves.
__global__ __launch_bounds__(1024) void PolyLinear_40218073760341_kernel(
    const float* __restrict__ X,   // (rows, 32)
    const float* __restrict__ W,   // (6544,)
    const float* __restrict__ Bp,  // (1,)
    float* __restrict__ out)       // (rows,)
{
    const int lane = threadIdx.x & 63;
    const int wave = threadIdx.x >> 6;  // part id 0..15
    const long base = (long)blockIdx.x * 128;

    __shared__ float Wl[6544];          // 26.2 KB staged weights
    __shared__ float partial[16][128];  // 8 KB reduce buffer

    // Stage W -> LDS (coalesced float4; 1636 vec4 over 1024 threads)
    {
        const float4* Wg = (const float4*)W;
        float4* Wd = (float4*)Wl;
        for (int i = threadIdx.x; i < 1636; i += 1024) Wd[i] = Wg[i];
    }

    // Load this lane's 2 rows into registers (coalesced float4).
    float x0[32], x1[32];
    {
        const float4* xr0 = (const float4*)(X + (base + lane) * 32);
        const float4* xr1 = (const float4*)(X + (base + 64 + lane) * 32);
#pragma unroll
        for (int i = 0; i < 8; ++i) {
            const float4 v = xr0[i];
            x0[4 * i + 0] = v.x; x0[4 * i + 1] = v.y;
            x0[4 * i + 2] = v.z; x0[4 * i + 3] = v.w;
            const float4 u = xr1[i];
            x1[4 * i + 0] = u.x; x1[4 * i + 1] = u.y;
            x1[4 * i + 2] = u.z; x1[4 * i + 3] = u.w;
        }
    }
    __syncthreads();  // Wl ready

    float acc0 = 0.0f, acc1 = 0.0f;
#define EVAL_CASE(P) case P: eval_part<P>(Wl, x0, x1, acc0, acc1); break;
    switch (wave) {
        EVAL_CASE(0)  EVAL_CASE(1)  EVAL_CASE(2)  EVAL_CASE(3)
        EVAL_CASE(4)  EVAL_CASE(5)  EVAL_CASE(6)  EVAL_CASE(7)
        EVAL_CASE(8)  EVAL_CASE(9)  EVAL_CASE(10) EVAL_CASE(11)
        EVAL_CASE(12) EVAL_CASE(13) EVAL_CASE(14) EVAL_CASE(15)
    }
#undef EVAL_CASE

    partial[wave][lane] = acc0;
    partial[wave][64 + lane] = acc1;
    __syncthreads();

    if (threadIdx.x < 128) {
        float r = Bp[0];
#pragma unroll
        for (int w = 0; w < 16; ++w) r += partial[w][threadIdx.x];
        out[base + threadIdx.x] = r;
    }
}

extern "C" void kernel_launch(void* const* d_in, const int* in_sizes, int n_in,
                              void* d_out, int out_size, void* d_ws, size_t ws_size,
                              hipStream_t stream) {
    const float* X  = (const float*)d_in[0];  // (32768, 32) fp32
    const float* W  = (const float*)d_in[1];  // (1, 6544) fp32
    const float* Bp = (const float*)d_in[2];  // (1,) fp32
    // d_in[3] = idx — deterministic, unused.
    float* out = (float*)d_out;

    const int rows = in_sizes[0] / 32;  // 32768
    const int grid = rows / 128;        // 256 blocks of 1024 threads
    PolyLinear_40218073760341_kernel<<<grid, 1024, 0, stream>>>(X, W, Bp, out);
}

// Round 3
// 71.247 us; speedup vs baseline: 1.5759x; 1.4725x over previous
//
#include <hip/hip_runtime.h>

// PolyLinear: out[i] = b + sum_j W[j] * prod_k x_aug[i, idx[j,k]]
// Deterministic lex-order enumeration: deg1 W[0..31], deg2 W[32..559] (a<=b),
// deg3 W[560..6543] (a<=b<=c). Factorization per row:
//   acc = sum_a W1[a]*x_a
//       + sum_{a<=b} (x_a*x_b) * ( W2[a,b] + sum_{c>=b} W3[a,b,c]*x_c )
//
// V4 vs V3 (47 us warm): V3 still spilled — 1024-thread blocks get a hard
// 64-VGPR allocation from the compiler (observed twice, with and without
// launch_bounds min-waves), while x0[]+x1[] alone need 64. WRITE_SIZE 67MB
// = 256 B/thread scratch writes confirmed it.
// Fix: 512-thread blocks (8 waves). Empirically (learn_hip m201) 512-thread
// blocks allocate up to ~250 VGPRs. 8-way balanced term split, 2 rows/lane,
// 128 rows/block, grid=256 -> 1 block/CU, 2 waves/SIMD.
// Expected regime: LDS-pipe bound (~1768 ds_read_b128 per CU @ ~10cy ~ 7.4us),
// VALU floor 3.0us.

#define NPART 8
#define TOTAL3 5984

__device__ __forceinline__ constexpr int off2(int a, int b) {
    // deg2 base 32; pairs (a<=b) lex order
    return 32 + 32 * a - (a * (a - 1)) / 2 + (b - a);
}

__device__ __forceinline__ constexpr int off3(int a, int b, int c) {
    // deg3 base 560; triples (a<=b<=c) lex order.
    // g3[a] = #triples with first index < a
    constexpr int g3[32] = {
        0,    528,  1024, 1489, 1924, 2330, 2708, 3059,
        3384, 3684, 3960, 4213, 4444, 4654, 4844, 5015,
        5168, 5304, 5424, 5529, 5620, 5698, 5764, 5819,
        5864, 5900, 5928, 5949, 5964, 5974, 5980, 5983};
    return 560 + g3[a] + 32 * (b - a) - ((b * (b - 1)) / 2 - (a * (a - 1)) / 2) + (c - b);
}

// #deg3 triples strictly before pair (a,b)'s c-run in lex order
__device__ __forceinline__ constexpr int cum3(int a, int b) {
    return off3(a, b, b) - 560;
}

// Balanced static ownership of pair (a,b): parts get ~equal deg3-FMA counts.
__device__ __forceinline__ constexpr int owner_of(int a, int b) {
    return (cum3(a, b) * NPART) / TOTAL3;  // monotone, 0..NPART-1
}

template <int PART>
__device__ __forceinline__ void eval_part(const float* __restrict__ Wl,
                                          const float (&x0)[32],
                                          const float (&x1)[32],
                                          float& acc0, float& acc1) {
    float a0 = 0.0f, a1 = 0.0f;
#pragma unroll
    for (int a = 0; a < 32; ++a) {
#pragma unroll
        for (int b = a; b < 32; ++b) {
            const int own = owner_of(a, b);  // folds post-unroll
            if (own == PART) {
                const float xa0 = x0[a], xa1 = x1[a];
                if (a == b) {  // attach deg1 term for feature a here
                    const float w1 = Wl[a];
                    a0 = __builtin_fmaf(w1, xa0, a0);
                    a1 = __builtin_fmaf(w1, xa1, a1);
                }
                float s0 = Wl[off2(a, b)];  // deg2 weight seeds the chain
                float s1 = s0;
#pragma unroll
                for (int c = b; c < 32; ++c) {
                    const float w = Wl[off3(a, b, c)];  // one LDS read, 2 FMAs
                    s0 = __builtin_fmaf(w, x0[c], s0);
                    s1 = __builtin_fmaf(w, x1[c], s1);
                }
                const float p0 = xa0 * x0[b];
                const float p1 = xa1 * x1[b];
                a0 = __builtin_fmaf(p0, s0, a0);
                a1 = __builtin_fmaf(p1, s1, a1);
            }
        }
    }
    acc0 = a0;
    acc1 = a1;
}

// Block: 512 threads = 8 waves, one balanced part each, same 128 rows.
// Each lane owns 2 rows (lane, lane+64). LDS reduce across waves.
__global__ __launch_bounds__(512) void PolyLinear_40218073760341_kernel(
    const float* __restrict__ X,   // (rows, 32)
    const float* __restrict__ W,   // (6544,)
    const float* __restrict__ Bp,  // (1,)
    float* __restrict__ out)       // (rows,)
{
    const int lane = threadIdx.x & 63;
    const int wave = threadIdx.x >> 6;  // part id 0..7
    const long base = (long)blockIdx.x * 128;

    __shared__ float Wl[6544];         // 26.2 KB staged weights
    __shared__ float partial[8][128];  // 4 KB reduce buffer

    // Stage W -> LDS (coalesced float4; 1636 vec4 over 512 threads)
    {
        const float4* Wg = (const float4*)W;
        float4* Wd = (float4*)Wl;
        for (int i = threadIdx.x; i < 1636; i += 512) Wd[i] = Wg[i];
    }

    // Load this lane's 2 rows into registers (coalesced float4).
    float x0[32], x1[32];
    {
        const float4* xr0 = (const float4*)(X + (base + lane) * 32);
        const float4* xr1 = (const float4*)(X + (base + 64 + lane) * 32);
#pragma unroll
        for (int i = 0; i < 8; ++i) {
            const float4 v = xr0[i];
            x0[4 * i + 0] = v.x; x0[4 * i + 1] = v.y;
            x0[4 * i + 2] = v.z; x0[4 * i + 3] = v.w;
            const float4 u = xr1[i];
            x1[4 * i + 0] = u.x; x1[4 * i + 1] = u.y;
            x1[4 * i + 2] = u.z; x1[4 * i + 3] = u.w;
        }
    }
    __syncthreads();  // Wl ready

    float acc0 = 0.0f, acc1 = 0.0f;
#define EVAL_CASE(P) case P: eval_part<P>(Wl, x0, x1, acc0, acc1); break;
    switch (wave) {
        EVAL_CASE(0) EVAL_CASE(1) EVAL_CASE(2) EVAL_CASE(3)
        EVAL_CASE(4) EVAL_CASE(5) EVAL_CASE(6) EVAL_CASE(7)
    }
#undef EVAL_CASE

    partial[wave][lane] = acc0;
    partial[wave][64 + lane] = acc1;
    __syncthreads();

    if (threadIdx.x < 128) {
        float r = Bp[0];
#pragma unroll
        for (int w = 0; w < 8; ++w) r += partial[w][threadIdx.x];
        out[base + threadIdx.x] = r;
    }
}

extern "C" void kernel_launch(void* const* d_in, const int* in_sizes, int n_in,
                              void* d_out, int out_size, void* d_ws, size_t ws_size,
                              hipStream_t stream) {
    const float* X  = (const float*)d_in[0];  // (32768, 32) fp32
    const float* W  = (const float*)d_in[1];  // (1, 6544) fp32
    const float* Bp = (const float*)d_in[2];  // (1,) fp32
    // d_in[3] = idx — deterministic, unused.
    float* out = (float*)d_out;

    const int rows = in_sizes[0] / 32;  // 32768
    const int grid = rows / 128;        // 256 blocks of 512 threads
    PolyLinear_40218073760341_kernel<<<grid, 512, 0, stream>>>(X, W, Bp, out);
}